// Round 4
// baseline (430.439 us; speedup 1.0000x reference)
//
#include <hip/hip_runtime.h>

#define SEQ 2048
#define HID 2048
#define NH 16
#define DK 128
#define NTOK 4096  // B*S

typedef __bf16 bf16x8 __attribute__((ext_vector_type(8)));
typedef float f32x4 __attribute__((ext_vector_type(4)));
typedef float f32x16 __attribute__((ext_vector_type(16)));
typedef unsigned int u32x4 __attribute__((ext_vector_type(4)));

__device__ __forceinline__ unsigned short f2bf(float f) {
  unsigned int u = __builtin_bit_cast(unsigned int, f);
  u += 0x7fffu + ((u >> 16) & 1u);
  return (unsigned short)(u >> 16);
}
__device__ __forceinline__ float bf2f(unsigned int lo16) {
  return __builtin_bit_cast(float, lo16 << 16);
}

__device__ __forceinline__ void async_cp16(const void* g, void* l) {
  __builtin_amdgcn_global_load_lds(
      (__attribute__((address_space(1))) void*)const_cast<void*>(g),
      (__attribute__((address_space(3))) void*)l, 16, 0, 0);
}

// ---- fp32 -> bf16 convert (x + 4 weights) + packed bf16 cos/sin table ------
// fcb[s*64+d] = (bf16(cos) | bf16(sin)<<16)
__global__ void convert_all_kernel(const float* __restrict__ x,
                                   const float* __restrict__ wq,
                                   const float* __restrict__ wk,
                                   const float* __restrict__ wv,
                                   const float* __restrict__ wo,
                                   const float* __restrict__ fc,
                                   unsigned short* __restrict__ xb,
                                   unsigned short* __restrict__ wqb,
                                   unsigned short* __restrict__ wkb,
                                   unsigned short* __restrict__ wvb,
                                   unsigned short* __restrict__ wob,
                                   unsigned int* __restrict__ fcb) {
  const int bid = blockIdx.x;
  if (bid >= 24576) {  // fc: 2048 s x 64 d
    const int idx = (bid - 24576) * 256 + threadIdx.x;  // [0, 131072)
    const int s = idx >> 6, d = idx & 63;
    const float2 cs = *(const float2*)(fc + s * 128 + 2 * d);
    fcb[idx] = (unsigned int)f2bf(cs.x) | ((unsigned int)f2bf(cs.y) << 16);
    return;
  }
  const float* src;
  unsigned short* dst;
  int base;
  if (bid < 8192) {               // x: 2,097,152 float4s
    src = x; dst = xb; base = bid;
  } else {
    const int t = (bid - 8192) >> 12;       // 4096 blocks per weight
    base = (bid - 8192) & 4095;
    src = (t == 0) ? wq : (t == 1) ? wk : (t == 2) ? wv : wo;
    dst = (t == 0) ? wqb : (t == 1) ? wkb : (t == 2) ? wvb : wob;
  }
  const int i = base * 256 + threadIdx.x;
  float4 v = ((const float4*)src)[i];
  ushort4 o;
  o.x = f2bf(v.x); o.y = f2bf(v.y); o.z = f2bf(v.z); o.w = f2bf(v.w);
  ((ushort4*)dst)[i] = o;
}

// ---------------- GEMM: C[M,2048] = A[M,2048] * W[2048,2048]^T (BT layout) ----
// 128x128 tile, BK=64, single-buffer LDS (R4-proven config: 32 KB, 2 barriers,
// launch_bounds(256,2) -> MfmaUtil ~45%, ~1000 TF; dbuf variants regress).
// One dispatch per weight (512 blocks = 2/CU, no tail) for rocprof attribution.
// mode 0/1 (Q/K): fused RoPE epilogue (pair partner via shfl_xor lane^1,
// packed bf16 cos/sin table); Q scaled by log2e/sqrt(dk) so flash can use
// exp2. mode 2 (V): transposed bf16 write. F32OUT (WO): plain f32 store.
template<bool F32OUT>
__global__ __launch_bounds__(256, 2)
void gemm_bt_kernel(const unsigned short* __restrict__ A,
                    const unsigned short* __restrict__ B,
                    unsigned short* __restrict__ Ob,
                    float* __restrict__ Of,
                    const unsigned int* __restrict__ fcb,
                    const int mode) {
  __shared__ alignas(16) unsigned short As[128 * 64];
  __shared__ alignas(16) unsigned short Bs[128 * 64];

  const int bx = blockIdx.x, by = blockIdx.y;
  const int col0 = bx * 128;
  const int row0 = by * 128;

  const int tid = threadIdx.x;
  const int wave = tid >> 6, lane = tid & 63;
  const int quad = lane >> 4, r = lane & 15;
  const int wm = wave >> 1, wn = wave & 1;
  const int jbase = wave * 256 + lane;

  f32x4 acc[4][4] = {};

  for (int k0 = 0; k0 < HID; k0 += 64) {
    for (int t = 0; t < 4; ++t) {
      const int j = jbase + t * 64;         // 0..1023 chunk id
      const int m = j >> 3;                 // tile row 0..127
      const int gc = (j & 7) ^ (m & 7);     // global chunk (swizzled)
      async_cp16(A + (size_t)(row0 + m) * HID + k0 + gc * 8, As + j * 8);
      async_cp16(B + (size_t)(col0 + m) * HID + k0 + gc * 8, Bs + j * 8);
    }
    __syncthreads();
    for (int kk = 0; kk < 2; ++kk) {
      bf16x8 af[4], bfr[4];
      for (int mt = 0; mt < 4; ++mt) {
        const int m = wm * 64 + mt * 16 + r;
        const int slot = (kk * 4 + quad) ^ (m & 7);
        af[mt] = __builtin_bit_cast(bf16x8, *(const u32x4*)(As + m * 64 + slot * 8));
      }
      for (int nt = 0; nt < 4; ++nt) {
        const int n = wn * 64 + nt * 16 + r;
        const int slot = (kk * 4 + quad) ^ (n & 7);
        bfr[nt] = __builtin_bit_cast(bf16x8, *(const u32x4*)(Bs + n * 64 + slot * 8));
      }
      for (int mt = 0; mt < 4; ++mt)
        for (int nt = 0; nt < 4; ++nt)
          acc[mt][nt] = __builtin_amdgcn_mfma_f32_16x16x32_bf16(
              af[mt], bfr[nt], acc[mt][nt], 0, 0, 0);
    }
    __syncthreads();
  }

  if (!F32OUT && mode == 2) {
    // transposed V write: Vt[(b*2048+col)][s], 4 consecutive tokens per lane
    for (int mt = 0; mt < 4; ++mt) {
      const int row = row0 + wm * 64 + mt * 16 + quad * 4;  // token base
      const int b = row >> 11, s = row & (SEQ - 1);
      for (int nt = 0; nt < 4; ++nt) {
        const int col = col0 + wn * 64 + nt * 16 + r;
        ushort4 pk;
        pk.x = f2bf(acc[mt][nt][0]);
        pk.y = f2bf(acc[mt][nt][1]);
        pk.z = f2bf(acc[mt][nt][2]);
        pk.w = f2bf(acc[mt][nt][3]);
        *(ushort4*)(Ob + ((size_t)(b * HID + col)) * SEQ + s) = pk;
      }
    }
    return;
  }

  if (!F32OUT) {
    // Q/K epilogue with fused RoPE (packed bf16 cos/sin).
    // Q also scaled by log2e/sqrt(dk) so flash softmax can use exp2 directly.
    const float qs = (mode == 0) ? 0.12751743f : 1.0f;
    for (int mt = 0; mt < 4; ++mt) {
      const int row = row0 + wm * 64 + mt * 16 + quad * 4;
      for (int nt = 0; nt < 4; ++nt) {
        const int col = col0 + wn * 64 + nt * 16 + r;
        const int d = (wn * 64 + nt * 16 + r) >> 1;
        for (int v = 0; v < 4; ++v) {
          const int s = (row + v) & (SEQ - 1);
          const unsigned int u = fcb[s * 64 + d];
          const float c = bf2f(u & 0xffffu), sn = bf2f(u >> 16);
          const float val = acc[mt][nt][v];
          const float par = __shfl_xor(val, 1, 64);
          const float res = (r & 1) ? (par * sn + val * c)
                                    : (val * c - par * sn);
          Ob[(size_t)(row + v) * HID + col] = f2bf(res * qs);
        }
      }
    }
    return;
  }

  for (int mt = 0; mt < 4; ++mt) {
    const int row = row0 + wm * 64 + mt * 16 + quad * 4;
    for (int nt = 0; nt < 4; ++nt) {
      const int col = col0 + wn * 64 + nt * 16 + r;
      for (int v = 0; v < 4; ++v)
        Of[(size_t)(row + v) * HID + col] = acc[mt][nt][v];
    }
  }
}

// ---------------- Flash attention (causal, online softmax, base-2) ----------
// v3: occupancy attack. R3 counters: VALUBusy 42% / MfmaUtil 18% / Occ 17.9%
// -> VALU-issue-bound at 2 blocks/CU (64 KB dbuf LDS + 512-block grid).
// Changes vs v2.1:
//  * single-buffer K/V (33 KB LDS) - TLP from 4 blocks/CU replaces dbuf
//  * un-paired grid: 1024 blocks, ONE 64-row q-tile each; LPT order
//    (descending qt) within each XCD chunk for dynamic load balance
//  * finite sentinel -30000 instead of -inf: kills all NaN-guard clamps
//    (16 fmax/body + merge clamps); exp2 flushes to 0 identically
//  * max3-friendly fmax triples; strength-reduced staging pointers
// Kept from v2: 32x32x16 swapped QK^T (lane owns softmax row), in-register
// P->A-frag repack (cvt_pk+permlane32_swap, T12), defer-max THR=8 (T13),
// setprio (T5), split-k key-half waves + LDS merge.
__global__ __launch_bounds__(256, 4)
void flash_attn_kernel(const unsigned short* __restrict__ Qb,
                       const unsigned short* __restrict__ Kb,
                       const unsigned short* __restrict__ VtG,
                       unsigned short* __restrict__ Ob) {
  __shared__ alignas(16) unsigned short Ks[64 * 128];   // 16 KB
  __shared__ alignas(16) unsigned short Vs[128 * 64];   // 16 KB
  __shared__ float Ml[4][64];                           // 1 KB  => 33 KB
  // merge-time aliases (all K/V reads done): obuf qgrp0 = Ks, qgrp1 = Vs
  // ([32][128] f32 = 16 KB each); Ml[wave][0..31]=m, [32..63]=l.

  // Grid mapping: hw bid -> XCD (bid&7, hw round-robin), 4 heads per XCD
  // (L2-resident K/V), descending qt (LPT schedule). Bijective on [0,1024).
  const int bid = blockIdx.x;
  const int local = bid >> 3;
  const int qt = 31 - (local >> 2);         // k-tiles = qt+1
  const int bh = (bid & 7) * 4 + (local & 3);
  const int tid = threadIdx.x, wave = tid >> 6, lane = tid & 63;
  const int l31 = lane & 31, hl = lane >> 5;
  const int qgrp = wave >> 1, ksub = wave & 1;
  const int tokbase = (bh >> 4) * SEQ;
  const int hh = bh & 15;
  const int q0 = qt * 64;
  const int qloc = qgrp * 32 + l31;         // q row within the 64-row tile

  const float NEG = -30000.f;               // finite -inf stand-in

  // strength-reduced staging sources (+= per k-tile; no per-tile addr calc)
  const unsigned short* kp[4];
  const unsigned short* vp[4];
#pragma unroll
  for (int t = 0; t < 4; ++t) {
    const int j = t * 256 + tid;
    const int n = j >> 4, slotK = j & 15, gcK = slotK ^ (n & 15);
    kp[t] = Kb + (size_t)(tokbase + n) * HID + hh * DK + gcK * 8;
    const int d = j >> 3, slotV = j & 7, gcV = slotV ^ (d & 7);
    vp[t] = VtG + (size_t)(bh * DK + d) * SEQ + gcV * 8;
  }

  // Q as B-fragment: lane holds Q[q=l31][ks*16 + hl*8 + j], ks=0..7 (K=128)
  u32x4 qf[8];
  {
    const unsigned short* qrow =
        Qb + (size_t)(tokbase + q0 + qloc) * HID + hh * DK;
#pragma unroll
    for (int ks = 0; ks < 8; ++ks)
      qf[ks] = *(const u32x4*)(qrow + ks * 16 + hl * 8);
  }

  f32x16 o[4] = {};                         // 32q x 128d partial (key-half)
  float m_i = NEG, l_i = 0.f;

  for (int kt = 0; kt <= qt; ++kt) {
    // ---- stage K/V tile kt (single buffer; barrier drains vmcnt) ---------
#pragma unroll
    for (int t = 0; t < 4; ++t) {
      async_cp16(kp[t], Ks + (t * 256 + tid) * 8);
      kp[t] += 64 * HID;
    }
#pragma unroll
    for (int t = 0; t < 4; ++t) {
      async_cp16(vp[t], Vs + (t * 256 + tid) * 8);
      vp[t] += 64;
    }
    __syncthreads();

    // --- S^T = K . Q^T : lane holds col q=l31, 16 key-rows ----------------
    f32x16 s = {};
    const unsigned short* krow = Ks + (size_t)(ksub * 32 + l31) * 128;
    __builtin_amdgcn_s_setprio(1);
#pragma unroll
    for (int ks = 0; ks < 8; ++ks) {
      const int slot = (ks * 2 + hl) ^ (lane & 15);
      const u32x4 kf = *(const u32x4*)(krow + slot * 8);
      s = __builtin_amdgcn_mfma_f32_32x32x16_bf16(
          __builtin_bit_cast(bf16x8, kf),
          __builtin_bit_cast(bf16x8, qf[ks]), s, 0, 0, 0);
    }
    __builtin_amdgcn_s_setprio(0);

    float sv[16];
#pragma unroll
    for (int r = 0; r < 16; ++r) sv[r] = s[r];
    if (kt == qt) {                         // causal mask on diagonal tile
#pragma unroll
      for (int r = 0; r < 16; ++r) {
        const int kloc = ksub * 32 + (r & 3) + 8 * (r >> 2) + 4 * hl;
        if (kloc > qloc) sv[r] = NEG;
      }
    }

    // row max: max3-friendly triples (16 -> 6 -> 2 -> 1)
    float t0 = fmaxf(fmaxf(sv[0], sv[1]), sv[2]);
    float t1 = fmaxf(fmaxf(sv[3], sv[4]), sv[5]);
    float t2 = fmaxf(fmaxf(sv[6], sv[7]), sv[8]);
    float t3 = fmaxf(fmaxf(sv[9], sv[10]), sv[11]);
    float t4 = fmaxf(fmaxf(sv[12], sv[13]), sv[14]);
    float mx = fmaxf(fmaxf(fmaxf(t0, t1), t2),
                     fmaxf(fmaxf(t3, t4), sv[15]));
    mx = fmaxf(mx, __shfl_xor(mx, 32, 64));

    if (!__all(mx <= m_i + 8.f)) {          // defer-max: rescale on growth
      const float mnew = fmaxf(m_i, mx);
      const float al = exp2f(m_i - mnew);   // finite args; flushes to 0
      m_i = mnew;
      l_i *= al;
#pragma unroll
      for (int dt = 0; dt < 4; ++dt)
#pragma unroll
        for (int r = 0; r < 16; ++r) o[dt][r] *= al;
    }

    float p[16];
    float rs = 0.f;
#pragma unroll
    for (int r = 0; r < 16; ++r) {
      p[r] = exp2f(sv[r] - m_i);            // masked: exp2(~-30030) = 0
      rs += p[r];
    }
    l_i += rs + __shfl_xor(rs, 32, 64);

    // --- pack P -> PV A-fragments (in-register half-transpose, T12) -------
    u32x4 af[2];
#pragma unroll
    for (int kk = 0; kk < 2; ++kk) {
      unsigned int a, b2, c2, d2;
      asm("v_cvt_pk_bf16_f32 %0, %1, %2"
          : "=v"(a) : "v"(p[8 * kk + 0]), "v"(p[8 * kk + 1]));
      asm("v_cvt_pk_bf16_f32 %0, %1, %2"
          : "=v"(b2) : "v"(p[8 * kk + 2]), "v"(p[8 * kk + 3]));
      asm("v_cvt_pk_bf16_f32 %0, %1, %2"
          : "=v"(c2) : "v"(p[8 * kk + 4]), "v"(p[8 * kk + 5]));
      asm("v_cvt_pk_bf16_f32 %0, %1, %2"
          : "=v"(d2) : "v"(p[8 * kk + 6]), "v"(p[8 * kk + 7]));
      asm("v_permlane32_swap_b32 %0, %1" : "+v"(a), "+v"(c2));
      asm("v_permlane32_swap_b32 %0, %1" : "+v"(b2), "+v"(d2));
      u32x4 t = {a, b2, c2, d2};
      af[kk] = t;
    }

    // --- O += P . V (V as B-fragment from d-major LDS) --------------------
    __builtin_amdgcn_s_setprio(1);
#pragma unroll
    for (int kk = 0; kk < 2; ++kk)
#pragma unroll
      for (int dt = 0; dt < 4; ++dt) {
        const int d = dt * 32 + l31;
        const int slot = (ksub * 4 + kk * 2 + hl) ^ (d & 7);
        const u32x4 vv = *(const u32x4*)(Vs + (size_t)d * 64 + slot * 8);
        o[dt] = __builtin_amdgcn_mfma_f32_32x32x16_bf16(
            __builtin_bit_cast(bf16x8, af[kk]),
            __builtin_bit_cast(bf16x8, vv), o[dt], 0, 0, 0);
      }
    __builtin_amdgcn_s_setprio(0);

    __syncthreads();  // all reads done before next stage overwrites
  }

  // --- merge key-half partials & write out (reuse idle K/V LDS) -----------
  float* obuf = (float*)(qgrp == 0 ? (void*)Ks : (void*)Vs);  // [32][128]
  if (ksub == 1) {
#pragma unroll
    for (int dt = 0; dt < 4; ++dt)
#pragma unroll
      for (int r = 0; r < 16; ++r) {
        const int qr = (r & 3) + 8 * (r >> 2) + 4 * hl;
        obuf[qr * 128 + dt * 32 + l31] = o[dt][r];
      }
  }
  if (lane < 32) {                          // both halves hold identical m,l
    Ml[wave][lane] = m_i;
    Ml[wave][32 + lane] = l_i;
  }
  __syncthreads();
  if (ksub == 0) {
    float f0[16], f1[16];
#pragma unroll
    for (int r = 0; r < 16; ++r) {
      const int qr = (r & 3) + 8 * (r >> 2) + 4 * hl;
      const float m0 = Ml[wave][qr];
      const float l0 = Ml[wave][32 + qr];
      const float m1 = Ml[wave + 1][qr];
      const float l1 = Ml[wave + 1][32 + qr];
      const float mm = fmaxf(m0, m1);
      const float a0 = exp2f(m0 - mm);      // finite; 0 for dead half
      const float a1 = exp2f(m1 - mm);
      const float li = 1.f / (l0 * a0 + l1 * a1);
      f0[r] = a0 * li;
      f1[r] = a1 * li;
    }
#pragma unroll
    for (int dt = 0; dt < 4; ++dt)
#pragma unroll
      for (int r = 0; r < 16; ++r) {
        const int qr = (r & 3) + 8 * (r >> 2) + 4 * hl;
        const float om =
            o[dt][r] * f0[r] + obuf[qr * 128 + dt * 32 + l31] * f1[r];
        Ob[(size_t)(tokbase + q0 + qgrp * 32 + qr) * HID + hh * DK +
           dt * 32 + l31] = f2bf(om);
      }
  }
}

// ---------------- host ------------------------------------------------------
extern "C" void kernel_launch(void* const* d_in, const int* in_sizes, int n_in,
                              void* d_out, int out_size, void* d_ws, size_t ws_size,
                              hipStream_t stream) {
  const float* x  = (const float*)d_in[0];
  const float* fc = (const float*)d_in[1];
  const float* wq = (const float*)d_in[2];
  const float* wk = (const float*)d_in[3];
  const float* wv = (const float*)d_in[4];
  const float* wo = (const float*)d_in[5];
  float* out = (float*)d_out;

  unsigned short* xb  = (unsigned short*)d_ws;     // [4096][2048]
  unsigned short* wqb = xb  + (size_t)NTOK * HID;  // [2048][2048] each
  unsigned short* wkb = wqb + (size_t)HID * HID;
  unsigned short* wvb = wkb + (size_t)HID * HID;
  unsigned short* wob = wvb + (size_t)HID * HID;
  unsigned short* qb  = wob + (size_t)HID * HID;   // [4096][2048]
  unsigned short* kb  = qb  + (size_t)NTOK * HID;
  unsigned short* vtb = kb  + (size_t)NTOK * HID;  // V^T [32*128][2048]
  unsigned short* ab  = vtb + (size_t)NTOK * HID;  // attn out [4096][2048]
  unsigned int*   fcb = (unsigned int*)(ab + (size_t)NTOK * HID);  // [2048*64]

  convert_all_kernel<<<24576 + 512, 256, 0, stream>>>(
      x, wq, wk, wv, wo, fc, xb, wqb, wkb, wvb, wob, fcb);

  gemm_bt_kernel<false><<<dim3(16, 32), 256, 0, stream>>>(
      xb, wqb, qb, nullptr, fcb, 0);
  gemm_bt_kernel<false><<<dim3(16, 32), 256, 0, stream>>>(
      xb, wkb, kb, nullptr, fcb, 1);
  gemm_bt_kernel<false><<<dim3(16, 32), 256, 0, stream>>>(
      xb, wvb, vtb, nullptr, fcb, 2);

  flash_attn_kernel<<<dim3(1024), 256, 0, stream>>>(qb, kb, vtb, ab);

  gemm_bt_kernel<true><<<dim3(16, 32), 256, 0, stream>>>(
      ab, wob, nullptr, out, fcb, 0);
}

// Round 5
// 362.127 us; speedup vs baseline: 1.1886x; 1.1886x over previous
//
#include <hip/hip_runtime.h>

#define SEQ 2048
#define HID 2048
#define NH 16
#define DK 128
#define NTOK 4096  // B*S

typedef __bf16 bf16x8 __attribute__((ext_vector_type(8)));
typedef float f32x4 __attribute__((ext_vector_type(4)));
typedef float f32x16 __attribute__((ext_vector_type(16)));
typedef unsigned int u32x4 __attribute__((ext_vector_type(4)));

__device__ __forceinline__ unsigned short f2bf(float f) {
  unsigned int u = __builtin_bit_cast(unsigned int, f);
  u += 0x7fffu + ((u >> 16) & 1u);
  return (unsigned short)(u >> 16);
}
__device__ __forceinline__ float bf2f(unsigned int lo16) {
  return __builtin_bit_cast(float, lo16 << 16);
}

__device__ __forceinline__ void async_cp16(const void* g, void* l) {
  __builtin_amdgcn_global_load_lds(
      (__attribute__((address_space(1))) void*)const_cast<void*>(g),
      (__attribute__((address_space(3))) void*)l, 16, 0, 0);
}

// ---- fp32 -> bf16 convert (x + 4 weights) + packed bf16 cos/sin table ------
// fcb[s*64+d] = (bf16(cos) | bf16(sin)<<16)
__global__ void convert_all_kernel(const float* __restrict__ x,
                                   const float* __restrict__ wq,
                                   const float* __restrict__ wk,
                                   const float* __restrict__ wv,
                                   const float* __restrict__ wo,
                                   const float* __restrict__ fc,
                                   unsigned short* __restrict__ xb,
                                   unsigned short* __restrict__ wqb,
                                   unsigned short* __restrict__ wkb,
                                   unsigned short* __restrict__ wvb,
                                   unsigned short* __restrict__ wob,
                                   unsigned int* __restrict__ fcb) {
  const int bid = blockIdx.x;
  if (bid >= 24576) {  // fc: 2048 s x 64 d
    const int idx = (bid - 24576) * 256 + threadIdx.x;  // [0, 131072)
    const int s = idx >> 6, d = idx & 63;
    const float2 cs = *(const float2*)(fc + s * 128 + 2 * d);
    fcb[idx] = (unsigned int)f2bf(cs.x) | ((unsigned int)f2bf(cs.y) << 16);
    return;
  }
  const float* src;
  unsigned short* dst;
  int base;
  if (bid < 8192) {               // x: 2,097,152 float4s
    src = x; dst = xb; base = bid;
  } else {
    const int t = (bid - 8192) >> 12;       // 4096 blocks per weight
    base = (bid - 8192) & 4095;
    src = (t == 0) ? wq : (t == 1) ? wk : (t == 2) ? wv : wo;
    dst = (t == 0) ? wqb : (t == 1) ? wkb : (t == 2) ? wvb : wob;
  }
  const int i = base * 256 + threadIdx.x;
  float4 v = ((const float4*)src)[i];
  ushort4 o;
  o.x = f2bf(v.x); o.y = f2bf(v.y); o.z = f2bf(v.z); o.w = f2bf(v.w);
  ((ushort4*)dst)[i] = o;
}

// ---------------- GEMM: C[M,2048] = A[M,2048] * W[2048,2048]^T (BT layout) ----
// 128x128 tile, BK=64, single-buffer LDS (R4-proven config: 32 KB, 2 barriers,
// launch_bounds(256,2) -> MfmaUtil ~45%, ~1000 TF; dbuf variants regress).
// One dispatch per weight (512 blocks = 2/CU, no tail) for rocprof attribution.
// mode 0/1 (Q/K): fused RoPE epilogue (pair partner via shfl_xor lane^1,
// packed bf16 cos/sin table); Q scaled by log2e/sqrt(dk) so flash can use
// exp2. mode 2 (V): transposed bf16 write. F32OUT (WO): plain f32 store.
template<bool F32OUT>
__global__ __launch_bounds__(256, 2)
void gemm_bt_kernel(const unsigned short* __restrict__ A,
                    const unsigned short* __restrict__ B,
                    unsigned short* __restrict__ Ob,
                    float* __restrict__ Of,
                    const unsigned int* __restrict__ fcb,
                    const int mode) {
  __shared__ alignas(16) unsigned short As[128 * 64];
  __shared__ alignas(16) unsigned short Bs[128 * 64];

  const int bx = blockIdx.x, by = blockIdx.y;
  const int col0 = bx * 128;
  const int row0 = by * 128;

  const int tid = threadIdx.x;
  const int wave = tid >> 6, lane = tid & 63;
  const int quad = lane >> 4, r = lane & 15;
  const int wm = wave >> 1, wn = wave & 1;
  const int jbase = wave * 256 + lane;

  f32x4 acc[4][4] = {};

  for (int k0 = 0; k0 < HID; k0 += 64) {
    for (int t = 0; t < 4; ++t) {
      const int j = jbase + t * 64;         // 0..1023 chunk id
      const int m = j >> 3;                 // tile row 0..127
      const int gc = (j & 7) ^ (m & 7);     // global chunk (swizzled)
      async_cp16(A + (size_t)(row0 + m) * HID + k0 + gc * 8, As + j * 8);
      async_cp16(B + (size_t)(col0 + m) * HID + k0 + gc * 8, Bs + j * 8);
    }
    __syncthreads();
    for (int kk = 0; kk < 2; ++kk) {
      bf16x8 af[4], bfr[4];
      for (int mt = 0; mt < 4; ++mt) {
        const int m = wm * 64 + mt * 16 + r;
        const int slot = (kk * 4 + quad) ^ (m & 7);
        af[mt] = __builtin_bit_cast(bf16x8, *(const u32x4*)(As + m * 64 + slot * 8));
      }
      for (int nt = 0; nt < 4; ++nt) {
        const int n = wn * 64 + nt * 16 + r;
        const int slot = (kk * 4 + quad) ^ (n & 7);
        bfr[nt] = __builtin_bit_cast(bf16x8, *(const u32x4*)(Bs + n * 64 + slot * 8));
      }
      for (int mt = 0; mt < 4; ++mt)
        for (int nt = 0; nt < 4; ++nt)
          acc[mt][nt] = __builtin_amdgcn_mfma_f32_16x16x32_bf16(
              af[mt], bfr[nt], acc[mt][nt], 0, 0, 0);
    }
    __syncthreads();
  }

  if (!F32OUT && mode == 2) {
    // transposed V write: Vt[(b*2048+col)][s], 4 consecutive tokens per lane
    for (int mt = 0; mt < 4; ++mt) {
      const int row = row0 + wm * 64 + mt * 16 + quad * 4;  // token base
      const int b = row >> 11, s = row & (SEQ - 1);
      for (int nt = 0; nt < 4; ++nt) {
        const int col = col0 + wn * 64 + nt * 16 + r;
        ushort4 pk;
        pk.x = f2bf(acc[mt][nt][0]);
        pk.y = f2bf(acc[mt][nt][1]);
        pk.z = f2bf(acc[mt][nt][2]);
        pk.w = f2bf(acc[mt][nt][3]);
        *(ushort4*)(Ob + ((size_t)(b * HID + col)) * SEQ + s) = pk;
      }
    }
    return;
  }

  if (!F32OUT) {
    // Q/K epilogue with fused RoPE (packed bf16 cos/sin).
    // Q also scaled by log2e/sqrt(dk) so flash softmax can use exp2 directly.
    const float qs = (mode == 0) ? 0.12751743f : 1.0f;
    for (int mt = 0; mt < 4; ++mt) {
      const int row = row0 + wm * 64 + mt * 16 + quad * 4;
      for (int nt = 0; nt < 4; ++nt) {
        const int col = col0 + wn * 64 + nt * 16 + r;
        const int d = (wn * 64 + nt * 16 + r) >> 1;
        for (int v = 0; v < 4; ++v) {
          const int s = (row + v) & (SEQ - 1);
          const unsigned int u = fcb[s * 64 + d];
          const float c = bf2f(u & 0xffffu), sn = bf2f(u >> 16);
          const float val = acc[mt][nt][v];
          const float par = __shfl_xor(val, 1, 64);
          const float res = (r & 1) ? (par * sn + val * c)
                                    : (val * c - par * sn);
          Ob[(size_t)(row + v) * HID + col] = f2bf(res * qs);
        }
      }
    }
    return;
  }

  for (int mt = 0; mt < 4; ++mt) {
    const int row = row0 + wm * 64 + mt * 16 + quad * 4;
    for (int nt = 0; nt < 4; ++nt) {
      const int col = col0 + wn * 64 + nt * 16 + r;
      for (int v = 0; v < 4; ++v)
        Of[(size_t)(row + v) * HID + col] = acc[mt][nt][v];
    }
  }
}

// ---------------- Flash attention (causal, online softmax, base-2) ----------
// v4: R3 structure + R4 trims, spill-free occupancy attack.
// R4 post-mortem: launch_bounds(256,4) forced VGPR 128->64 -> ~85 f32/thread
// scratch spill (WRITE_SIZE 16->105 MB) -> 140 us. R3's (256,2) compiled this
// body to EXACTLY 128 VGPR (the 4-waves/SIMD boundary, m69) with zero spill;
// R3 was LDS-limited (64 KB dbuf -> 2 blocks/CU). So: single-buffer K/V
// (33 KB -> 4 blocks/CU possible) + launch_bounds(256,2) (VGPR stays 128).
// Block-level TLP (4 indep blocks/CU) replaces dbuf for latency hiding.
//  * unpaired grid: 1024 blocks, ONE 64-row q-tile each; LPT order
//    (descending qt) within each XCD chunk; 4 heads/XCD (L2-resident K/V)
//  * finite sentinel -30000 (no NaN clamps); max3-friendly fmax triples
//  * addresses recomputed in stage() (register-lean; R4's pointer arrays
//    cost 16 live VGPRs)
// Kept: 32x32x16 swapped QK^T (lane owns softmax row), in-register P repack
// (cvt_pk+permlane32_swap, T12), defer-max THR=8 (T13), setprio (T5),
// split-k key-half waves + LDS merge.
__global__ __launch_bounds__(256, 2)
void flash_attn_kernel(const unsigned short* __restrict__ Qb,
                       const unsigned short* __restrict__ Kb,
                       const unsigned short* __restrict__ VtG,
                       unsigned short* __restrict__ Ob) {
  __shared__ alignas(16) unsigned short Ks[64 * 128];   // 16 KB
  __shared__ alignas(16) unsigned short Vs[128 * 64];   // 16 KB
  __shared__ float Ml[4][64];                           // 1 KB  => 33 KB
  // merge-time aliases (all K/V reads done): obuf qgrp0 = Ks, qgrp1 = Vs
  // ([32][128] f32 = 16 KB each); Ml[wave][0..31]=m, [32..63]=l.

  // Grid mapping: hw bid -> XCD (bid&7), 4 heads per XCD (L2-resident K/V),
  // descending qt (LPT schedule). Bijective on [0,1024).
  const int bid = blockIdx.x;
  const int local = bid >> 3;
  const int qt = 31 - (local >> 2);         // k-tiles = qt+1
  const int bh = (bid & 7) * 4 + (local & 3);
  const int tid = threadIdx.x, wave = tid >> 6, lane = tid & 63;
  const int l31 = lane & 31, hl = lane >> 5;
  const int qgrp = wave >> 1, ksub = wave & 1;
  const int tokbase = (bh >> 4) * SEQ;
  const int hh = bh & 15;
  const int q0 = qt * 64;
  const int qloc = qgrp * 32 + l31;         // q row within the 64-row tile

  const float NEG = -30000.f;               // finite -inf stand-in

  auto stage = [&](int kt) {
#pragma unroll
    for (int t = 0; t < 4; ++t) {
      const int j = t * 256 + tid;
      const int n = j >> 4, slot = j & 15;
      const int gc = slot ^ (n & 15);
      async_cp16(Kb + (size_t)(tokbase + kt * 64 + n) * HID + hh * DK + gc * 8,
                 Ks + j * 8);
    }
#pragma unroll
    for (int t = 0; t < 4; ++t) {
      const int j = t * 256 + tid;
      const int d = j >> 3, slot = j & 7;
      const int gc = slot ^ (d & 7);
      async_cp16(VtG + (size_t)(bh * DK + d) * SEQ + kt * 64 + gc * 8,
                 Vs + j * 8);
    }
  };

  // Q as B-fragment: lane holds Q[q=l31][ks*16 + hl*8 + j], ks=0..7 (K=128)
  u32x4 qf[8];
  {
    const unsigned short* qrow =
        Qb + (size_t)(tokbase + q0 + qloc) * HID + hh * DK;
#pragma unroll
    for (int ks = 0; ks < 8; ++ks)
      qf[ks] = *(const u32x4*)(qrow + ks * 16 + hl * 8);
  }

  f32x16 o[4] = {};                         // 32q x 128d partial (key-half)
  float m_i = NEG, l_i = 0.f;

  for (int kt = 0; kt <= qt; ++kt) {
    // ---- stage K/V tile kt (single buffer; barrier drains vmcnt) ---------
    stage(kt);
    __syncthreads();

    // --- S^T = K . Q^T : lane holds col q=l31, 16 key-rows ----------------
    f32x16 s = {};
    const unsigned short* krow = Ks + (size_t)(ksub * 32 + l31) * 128;
    __builtin_amdgcn_s_setprio(1);
#pragma unroll
    for (int ks = 0; ks < 8; ++ks) {
      const int slot = (ks * 2 + hl) ^ (lane & 15);
      const u32x4 kf = *(const u32x4*)(krow + slot * 8);
      s = __builtin_amdgcn_mfma_f32_32x32x16_bf16(
          __builtin_bit_cast(bf16x8, kf),
          __builtin_bit_cast(bf16x8, qf[ks]), s, 0, 0, 0);
    }
    __builtin_amdgcn_s_setprio(0);

    float sv[16];
#pragma unroll
    for (int r = 0; r < 16; ++r) sv[r] = s[r];
    if (kt == qt) {                         // causal mask on diagonal tile
#pragma unroll
      for (int r = 0; r < 16; ++r) {
        const int kloc = ksub * 32 + (r & 3) + 8 * (r >> 2) + 4 * hl;
        if (kloc > qloc) sv[r] = NEG;
      }
    }

    // row max: max3-friendly triples (16 -> 6 -> 2 -> 1)
    float t0 = fmaxf(fmaxf(sv[0], sv[1]), sv[2]);
    float t1 = fmaxf(fmaxf(sv[3], sv[4]), sv[5]);
    float t2 = fmaxf(fmaxf(sv[6], sv[7]), sv[8]);
    float t3 = fmaxf(fmaxf(sv[9], sv[10]), sv[11]);
    float t4 = fmaxf(fmaxf(sv[12], sv[13]), sv[14]);
    float mx = fmaxf(fmaxf(fmaxf(t0, t1), t2),
                     fmaxf(fmaxf(t3, t4), sv[15]));
    mx = fmaxf(mx, __shfl_xor(mx, 32, 64));

    if (!__all(mx <= m_i + 8.f)) {          // defer-max: rescale on growth
      const float mnew = fmaxf(m_i, mx);
      const float al = exp2f(m_i - mnew);   // finite args; flushes to 0
      m_i = mnew;
      l_i *= al;
#pragma unroll
      for (int dt = 0; dt < 4; ++dt)
#pragma unroll
        for (int r = 0; r < 16; ++r) o[dt][r] *= al;
    }

    float p[16];
    float rs = 0.f;
#pragma unroll
    for (int r = 0; r < 16; ++r) {
      p[r] = exp2f(sv[r] - m_i);            // masked: exp2(~-30030) = 0
      rs += p[r];
    }
    l_i += rs + __shfl_xor(rs, 32, 64);

    // --- pack P -> PV A-fragments (in-register half-transpose, T12) -------
    u32x4 af[2];
#pragma unroll
    for (int kk = 0; kk < 2; ++kk) {
      unsigned int a, b2, c2, d2;
      asm("v_cvt_pk_bf16_f32 %0, %1, %2"
          : "=v"(a) : "v"(p[8 * kk + 0]), "v"(p[8 * kk + 1]));
      asm("v_cvt_pk_bf16_f32 %0, %1, %2"
          : "=v"(b2) : "v"(p[8 * kk + 2]), "v"(p[8 * kk + 3]));
      asm("v_cvt_pk_bf16_f32 %0, %1, %2"
          : "=v"(c2) : "v"(p[8 * kk + 4]), "v"(p[8 * kk + 5]));
      asm("v_cvt_pk_bf16_f32 %0, %1, %2"
          : "=v"(d2) : "v"(p[8 * kk + 6]), "v"(p[8 * kk + 7]));
      asm("v_permlane32_swap_b32 %0, %1" : "+v"(a), "+v"(c2));
      asm("v_permlane32_swap_b32 %0, %1" : "+v"(b2), "+v"(d2));
      u32x4 t = {a, b2, c2, d2};
      af[kk] = t;
    }

    // --- O += P . V (V as B-fragment from d-major LDS) --------------------
    __builtin_amdgcn_s_setprio(1);
#pragma unroll
    for (int kk = 0; kk < 2; ++kk)
#pragma unroll
      for (int dt = 0; dt < 4; ++dt) {
        const int d = dt * 32 + l31;
        const int slot = (ksub * 4 + kk * 2 + hl) ^ (d & 7);
        const u32x4 vv = *(const u32x4*)(Vs + (size_t)d * 64 + slot * 8);
        o[dt] = __builtin_amdgcn_mfma_f32_32x32x16_bf16(
            __builtin_bit_cast(bf16x8, af[kk]),
            __builtin_bit_cast(bf16x8, vv), o[dt], 0, 0, 0);
      }
    __builtin_amdgcn_s_setprio(0);

    __syncthreads();  // all reads done before next stage overwrites
  }

  // --- merge key-half partials & write out (reuse idle K/V LDS) -----------
  float* obuf = (float*)(qgrp == 0 ? (void*)Ks : (void*)Vs);  // [32][128]
  if (ksub == 1) {
#pragma unroll
    for (int dt = 0; dt < 4; ++dt)
#pragma unroll
      for (int r = 0; r < 16; ++r) {
        const int qr = (r & 3) + 8 * (r >> 2) + 4 * hl;
        obuf[qr * 128 + dt * 32 + l31] = o[dt][r];
      }
  }
  if (lane < 32) {                          // both halves hold identical m,l
    Ml[wave][lane] = m_i;
    Ml[wave][32 + lane] = l_i;
  }
  __syncthreads();
  if (ksub == 0) {
    float f0[16], f1[16];
#pragma unroll
    for (int r = 0; r < 16; ++r) {
      const int qr = (r & 3) + 8 * (r >> 2) + 4 * hl;
      const float m0 = Ml[wave][qr];
      const float l0 = Ml[wave][32 + qr];
      const float m1 = Ml[wave + 1][qr];
      const float l1 = Ml[wave + 1][32 + qr];
      const float mm = fmaxf(m0, m1);
      const float a0 = exp2f(m0 - mm);      // finite; 0 for dead half
      const float a1 = exp2f(m1 - mm);
      const float li = 1.f / (l0 * a0 + l1 * a1);
      f0[r] = a0 * li;
      f1[r] = a1 * li;
    }
#pragma unroll
    for (int dt = 0; dt < 4; ++dt)
#pragma unroll
      for (int r = 0; r < 16; ++r) {
        const int qr = (r & 3) + 8 * (r >> 2) + 4 * hl;
        const float om =
            o[dt][r] * f0[r] + obuf[qr * 128 + dt * 32 + l31] * f1[r];
        Ob[(size_t)(tokbase + q0 + qgrp * 32 + qr) * HID + hh * DK +
           dt * 32 + l31] = f2bf(om);
      }
  }
}

// ---------------- host ------------------------------------------------------
extern "C" void kernel_launch(void* const* d_in, const int* in_sizes, int n_in,
                              void* d_out, int out_size, void* d_ws, size_t ws_size,
                              hipStream_t stream) {
  const float* x  = (const float*)d_in[0];
  const float* fc = (const float*)d_in[1];
  const float* wq = (const float*)d_in[2];
  const float* wk = (const float*)d_in[3];
  const float* wv = (const float*)d_in[4];
  const float* wo = (const float*)d_in[5];
  float* out = (float*)d_out;

  unsigned short* xb  = (unsigned short*)d_ws;     // [4096][2048]
  unsigned short* wqb = xb  + (size_t)NTOK * HID;  // [2048][2048] each
  unsigned short* wkb = wqb + (size_t)HID * HID;
  unsigned short* wvb = wkb + (size_t)HID * HID;
  unsigned short* wob = wvb + (size_t)HID * HID;
  unsigned short* qb  = wob + (size_t)HID * HID;   // [4096][2048]
  unsigned short* kb  = qb  + (size_t)NTOK * HID;
  unsigned short* vtb = kb  + (size_t)NTOK * HID;  // V^T [32*128][2048]
  unsigned short* ab  = vtb + (size_t)NTOK * HID;  // attn out [4096][2048]
  unsigned int*   fcb = (unsigned int*)(ab + (size_t)NTOK * HID);  // [2048*64]

  convert_all_kernel<<<24576 + 512, 256, 0, stream>>>(
      x, wq, wk, wv, wo, fc, xb, wqb, wkb, wvb, wob, fcb);

  gemm_bt_kernel<false><<<dim3(16, 32), 256, 0, stream>>>(
      xb, wqb, qb, nullptr, fcb, 0);
  gemm_bt_kernel<false><<<dim3(16, 32), 256, 0, stream>>>(
      xb, wkb, kb, nullptr, fcb, 1);
  gemm_bt_kernel<false><<<dim3(16, 32), 256, 0, stream>>>(
      xb, wvb, vtb, nullptr, fcb, 2);

  flash_attn_kernel<<<dim3(1024), 256, 0, stream>>>(qb, kb, vtb, ab);

  gemm_bt_kernel<true><<<dim3(16, 32), 256, 0, stream>>>(
      ab, wob, nullptr, out, fcb, 0);
}

// Round 6
// 359.400 us; speedup vs baseline: 1.1977x; 1.0076x over previous
//
#include <hip/hip_runtime.h>

#define SEQ 2048
#define HID 2048
#define NH 16
#define DK 128
#define NTOK 4096  // B*S

typedef __bf16 bf16x8 __attribute__((ext_vector_type(8)));
typedef float f32x4 __attribute__((ext_vector_type(4)));
typedef float f32x16 __attribute__((ext_vector_type(16)));
typedef unsigned int u32x4 __attribute__((ext_vector_type(4)));

__device__ __forceinline__ unsigned short f2bf(float f) {
  unsigned int u = __builtin_bit_cast(unsigned int, f);
  u += 0x7fffu + ((u >> 16) & 1u);
  return (unsigned short)(u >> 16);
}
__device__ __forceinline__ float bf2f(unsigned int lo16) {
  return __builtin_bit_cast(float, lo16 << 16);
}

__device__ __forceinline__ void async_cp16(const void* g, void* l) {
  __builtin_amdgcn_global_load_lds(
      (__attribute__((address_space(1))) void*)const_cast<void*>(g),
      (__attribute__((address_space(3))) void*)l, 16, 0, 0);
}

// ---- fp32 -> bf16 convert (x + 4 weights) + packed bf16 cos/sin table ------
// fcb[s*64+d] = (bf16(cos) | bf16(sin)<<16)
__global__ void convert_all_kernel(const float* __restrict__ x,
                                   const float* __restrict__ wq,
                                   const float* __restrict__ wk,
                                   const float* __restrict__ wv,
                                   const float* __restrict__ wo,
                                   const float* __restrict__ fc,
                                   unsigned short* __restrict__ xb,
                                   unsigned short* __restrict__ wqb,
                                   unsigned short* __restrict__ wkb,
                                   unsigned short* __restrict__ wvb,
                                   unsigned short* __restrict__ wob,
                                   unsigned int* __restrict__ fcb) {
  const int bid = blockIdx.x;
  if (bid >= 24576) {  // fc: 2048 s x 64 d
    const int idx = (bid - 24576) * 256 + threadIdx.x;  // [0, 131072)
    const int s = idx >> 6, d = idx & 63;
    const float2 cs = *(const float2*)(fc + s * 128 + 2 * d);
    fcb[idx] = (unsigned int)f2bf(cs.x) | ((unsigned int)f2bf(cs.y) << 16);
    return;
  }
  const float* src;
  unsigned short* dst;
  int base;
  if (bid < 8192) {               // x: 2,097,152 float4s
    src = x; dst = xb; base = bid;
  } else {
    const int t = (bid - 8192) >> 12;       // 4096 blocks per weight
    base = (bid - 8192) & 4095;
    src = (t == 0) ? wq : (t == 1) ? wk : (t == 2) ? wv : wo;
    dst = (t == 0) ? wqb : (t == 1) ? wkb : (t == 2) ? wvb : wob;
  }
  const int i = base * 256 + threadIdx.x;
  float4 v = ((const float4*)src)[i];
  ushort4 o;
  o.x = f2bf(v.x); o.y = f2bf(v.y); o.z = f2bf(v.z); o.w = f2bf(v.w);
  ((ushort4*)dst)[i] = o;
}

// ---------------- GEMM: C[M,2048] = A[M,2048] * W[2048,2048]^T (BT layout) ----
// 128x128 tile, BK=64, single-buffer LDS (R4-proven config: 32 KB, 2 barriers,
// launch_bounds(256,2) -> MfmaUtil ~45%, ~1000 TF; dbuf variants regress).
// One dispatch per weight (512 blocks = 2/CU, no tail) for rocprof attribution.
// mode 0/1 (Q/K): fused RoPE epilogue (pair partner via shfl_xor lane^1,
// packed bf16 cos/sin table); Q scaled by log2e/sqrt(dk) so flash can use
// exp2. mode 2 (V): transposed bf16 write. F32OUT (WO): plain f32 store.
template<bool F32OUT>
__global__ __launch_bounds__(256, 2)
void gemm_bt_kernel(const unsigned short* __restrict__ A,
                    const unsigned short* __restrict__ B,
                    unsigned short* __restrict__ Ob,
                    float* __restrict__ Of,
                    const unsigned int* __restrict__ fcb,
                    const int mode) {
  __shared__ alignas(16) unsigned short As[128 * 64];
  __shared__ alignas(16) unsigned short Bs[128 * 64];

  const int bx = blockIdx.x, by = blockIdx.y;
  const int col0 = bx * 128;
  const int row0 = by * 128;

  const int tid = threadIdx.x;
  const int wave = tid >> 6, lane = tid & 63;
  const int quad = lane >> 4, r = lane & 15;
  const int wm = wave >> 1, wn = wave & 1;
  const int jbase = wave * 256 + lane;

  f32x4 acc[4][4] = {};

  for (int k0 = 0; k0 < HID; k0 += 64) {
    for (int t = 0; t < 4; ++t) {
      const int j = jbase + t * 64;         // 0..1023 chunk id
      const int m = j >> 3;                 // tile row 0..127
      const int gc = (j & 7) ^ (m & 7);     // global chunk (swizzled)
      async_cp16(A + (size_t)(row0 + m) * HID + k0 + gc * 8, As + j * 8);
      async_cp16(B + (size_t)(col0 + m) * HID + k0 + gc * 8, Bs + j * 8);
    }
    __syncthreads();
    for (int kk = 0; kk < 2; ++kk) {
      bf16x8 af[4], bfr[4];
      for (int mt = 0; mt < 4; ++mt) {
        const int m = wm * 64 + mt * 16 + r;
        const int slot = (kk * 4 + quad) ^ (m & 7);
        af[mt] = __builtin_bit_cast(bf16x8, *(const u32x4*)(As + m * 64 + slot * 8));
      }
      for (int nt = 0; nt < 4; ++nt) {
        const int n = wn * 64 + nt * 16 + r;
        const int slot = (kk * 4 + quad) ^ (n & 7);
        bfr[nt] = __builtin_bit_cast(bf16x8, *(const u32x4*)(Bs + n * 64 + slot * 8));
      }
      for (int mt = 0; mt < 4; ++mt)
        for (int nt = 0; nt < 4; ++nt)
          acc[mt][nt] = __builtin_amdgcn_mfma_f32_16x16x32_bf16(
              af[mt], bfr[nt], acc[mt][nt], 0, 0, 0);
    }
    __syncthreads();
  }

  if (!F32OUT && mode == 2) {
    // transposed V write: Vt[(b*2048+col)][s], 4 consecutive tokens per lane
    for (int mt = 0; mt < 4; ++mt) {
      const int row = row0 + wm * 64 + mt * 16 + quad * 4;  // token base
      const int b = row >> 11, s = row & (SEQ - 1);
      for (int nt = 0; nt < 4; ++nt) {
        const int col = col0 + wn * 64 + nt * 16 + r;
        ushort4 pk;
        pk.x = f2bf(acc[mt][nt][0]);
        pk.y = f2bf(acc[mt][nt][1]);
        pk.z = f2bf(acc[mt][nt][2]);
        pk.w = f2bf(acc[mt][nt][3]);
        *(ushort4*)(Ob + ((size_t)(b * HID + col)) * SEQ + s) = pk;
      }
    }
    return;
  }

  if (!F32OUT) {
    // Q/K epilogue with fused RoPE (packed bf16 cos/sin).
    // Q also scaled by log2e/sqrt(dk) so flash softmax can use exp2 directly.
    const float qs = (mode == 0) ? 0.12751743f : 1.0f;
    for (int mt = 0; mt < 4; ++mt) {
      const int row = row0 + wm * 64 + mt * 16 + quad * 4;
      for (int nt = 0; nt < 4; ++nt) {
        const int col = col0 + wn * 64 + nt * 16 + r;
        const int d = (wn * 64 + nt * 16 + r) >> 1;
        for (int v = 0; v < 4; ++v) {
          const int s = (row + v) & (SEQ - 1);
          const unsigned int u = fcb[s * 64 + d];
          const float c = bf2f(u & 0xffffu), sn = bf2f(u >> 16);
          const float val = acc[mt][nt][v];
          const float par = __shfl_xor(val, 1, 64);
          const float res = (r & 1) ? (par * sn + val * c)
                                    : (val * c - par * sn);
          Ob[(size_t)(row + v) * HID + col] = f2bf(res * qs);
        }
      }
    }
    return;
  }

  for (int mt = 0; mt < 4; ++mt) {
    const int row = row0 + wm * 64 + mt * 16 + quad * 4;
    for (int nt = 0; nt < 4; ++nt) {
      const int col = col0 + wn * 64 + nt * 16 + r;
      for (int v = 0; v < 4; ++v)
        Of[(size_t)(row + v) * HID + col] = acc[mt][nt][v];
    }
  }
}

// ---------------- Flash attention (causal, online softmax, base-2) ----------
// v5: T14 async-STAGE split. R5 post-mortem: grid shape caps avg residency at
// ~2 blocks/CU (1024 ragged blocks), so per-step load latency CANNOT be hidden
// by TLP; R5 issues global_load_lds immediately before __syncthreads, whose
// vmcnt(0) drain exposes full L2/HBM latency every k-tile. Fix: prefetch tile
// kt+1 into REGISTERS (8 x u32x4) during compute of kt; at step boundary only
// a cheap VGPR->LDS ds_write + barrier. Registers are the double buffer -> LDS
// stays 33 KB. Loads get a full compute phase (~500 cyc) to land; steady-state
// vmcnt drain ~0. (+48 VGPR expected, ~140 total, within (256,2) budget.)
// Kept from v4: unpaired 1024-block LPT grid, 4 heads/XCD, finite sentinel
// -30000, max3 triples, 32x32x16 swapped QK^T (lane owns softmax row),
// in-register P repack (cvt_pk+permlane32_swap, T12), defer-max THR=8 (T13),
// setprio (T5), split-k key-half waves + LDS merge.
__global__ __launch_bounds__(256, 2)
void flash_attn_kernel(const unsigned short* __restrict__ Qb,
                       const unsigned short* __restrict__ Kb,
                       const unsigned short* __restrict__ VtG,
                       unsigned short* __restrict__ Ob) {
  __shared__ alignas(16) unsigned short Ks[64 * 128];   // 16 KB
  __shared__ alignas(16) unsigned short Vs[128 * 64];   // 16 KB
  __shared__ float Ml[4][64];                           // 1 KB  => 33 KB
  // merge-time aliases (all K/V reads done): obuf qgrp0 = Ks, qgrp1 = Vs
  // ([32][128] f32 = 16 KB each); Ml[wave][0..31]=m, [32..63]=l.

  // Grid mapping: hw bid -> XCD (bid&7), 4 heads per XCD (L2-resident K/V),
  // descending qt (LPT schedule). Bijective on [0,1024).
  const int bid = blockIdx.x;
  const int local = bid >> 3;
  const int qt = 31 - (local >> 2);         // k-tiles = qt+1
  const int bh = (bid & 7) * 4 + (local & 3);
  const int tid = threadIdx.x, wave = tid >> 6, lane = tid & 63;
  const int l31 = lane & 31, hl = lane >> 5;
  const int qgrp = wave >> 1, ksub = wave & 1;
  const int tokbase = (bh >> 4) * SEQ;
  const int hh = bh & 15;
  const int q0 = qt * 64;
  const int qloc = qgrp * 32 + l31;         // q row within the 64-row tile

  const float NEG = -30000.f;               // finite -inf stand-in

  // ---- T14 register double-buffer staging ----------------------------------
  u32x4 kd[4], vd[4];                       // next-tile K/V (16B/thread each)
  auto issue = [&](int kt) {                // global -> regs (swizzled source)
#pragma unroll
    for (int t = 0; t < 4; ++t) {
      const int j = t * 256 + tid;
      const int n = j >> 4, slot = j & 15;
      const int gc = slot ^ (n & 15);
      kd[t] = *(const u32x4*)(Kb + (size_t)(tokbase + kt * 64 + n) * HID +
                              hh * DK + gc * 8);
    }
#pragma unroll
    for (int t = 0; t < 4; ++t) {
      const int j = t * 256 + tid;
      const int d = j >> 3, slot = j & 7;
      const int gc = slot ^ (d & 7);
      vd[t] = *(const u32x4*)(VtG + (size_t)(bh * DK + d) * SEQ + kt * 64 +
                              gc * 8);
    }
  };
  auto lwrite = [&]() {                     // regs -> LDS (linear dest)
#pragma unroll
    for (int t = 0; t < 4; ++t)
      *(u32x4*)(Ks + (t * 256 + tid) * 8) = kd[t];
#pragma unroll
    for (int t = 0; t < 4; ++t)
      *(u32x4*)(Vs + (t * 256 + tid) * 8) = vd[t];
  };

  // Q as B-fragment: lane holds Q[q=l31][ks*16 + hl*8 + j], ks=0..7 (K=128)
  u32x4 qf[8];
  {
    const unsigned short* qrow =
        Qb + (size_t)(tokbase + q0 + qloc) * HID + hh * DK;
#pragma unroll
    for (int ks = 0; ks < 8; ++ks)
      qf[ks] = *(const u32x4*)(qrow + ks * 16 + hl * 8);
  }

  f32x16 o[4] = {};                         // 32q x 128d partial (key-half)
  float m_i = NEG, l_i = 0.f;

  issue(0);                                 // prologue prefetch (latency once)
  for (int kt = 0; kt <= qt; ++kt) {
    // ---- commit prefetched tile to LDS (vmcnt wait is ~0 in steady state) --
    lwrite();
    __syncthreads();                        // writes visible to all waves
    if (kt < qt) issue(kt + 1);             // next tile in flight under compute

    // --- S^T = K . Q^T : lane holds col q=l31, 16 key-rows ----------------
    f32x16 s = {};
    const unsigned short* krow = Ks + (size_t)(ksub * 32 + l31) * 128;
    __builtin_amdgcn_s_setprio(1);
#pragma unroll
    for (int ks = 0; ks < 8; ++ks) {
      const int slot = (ks * 2 + hl) ^ (lane & 15);
      const u32x4 kf = *(const u32x4*)(krow + slot * 8);
      s = __builtin_amdgcn_mfma_f32_32x32x16_bf16(
          __builtin_bit_cast(bf16x8, kf),
          __builtin_bit_cast(bf16x8, qf[ks]), s, 0, 0, 0);
    }
    __builtin_amdgcn_s_setprio(0);

    float sv[16];
#pragma unroll
    for (int r = 0; r < 16; ++r) sv[r] = s[r];
    if (kt == qt) {                         // causal mask on diagonal tile
#pragma unroll
      for (int r = 0; r < 16; ++r) {
        const int kloc = ksub * 32 + (r & 3) + 8 * (r >> 2) + 4 * hl;
        if (kloc > qloc) sv[r] = NEG;
      }
    }

    // row max: max3-friendly triples (16 -> 6 -> 2 -> 1)
    float t0 = fmaxf(fmaxf(sv[0], sv[1]), sv[2]);
    float t1 = fmaxf(fmaxf(sv[3], sv[4]), sv[5]);
    float t2 = fmaxf(fmaxf(sv[6], sv[7]), sv[8]);
    float t3 = fmaxf(fmaxf(sv[9], sv[10]), sv[11]);
    float t4 = fmaxf(fmaxf(sv[12], sv[13]), sv[14]);
    float mx = fmaxf(fmaxf(fmaxf(t0, t1), t2),
                     fmaxf(fmaxf(t3, t4), sv[15]));
    mx = fmaxf(mx, __shfl_xor(mx, 32, 64));

    if (!__all(mx <= m_i + 8.f)) {          // defer-max: rescale on growth
      const float mnew = fmaxf(m_i, mx);
      const float al = exp2f(m_i - mnew);   // finite args; flushes to 0
      m_i = mnew;
      l_i *= al;
#pragma unroll
      for (int dt = 0; dt < 4; ++dt)
#pragma unroll
        for (int r = 0; r < 16; ++r) o[dt][r] *= al;
    }

    float p[16];
    float rs = 0.f;
#pragma unroll
    for (int r = 0; r < 16; ++r) {
      p[r] = exp2f(sv[r] - m_i);            // masked: exp2(~-30030) = 0
      rs += p[r];
    }
    l_i += rs + __shfl_xor(rs, 32, 64);

    // --- pack P -> PV A-fragments (in-register half-transpose, T12) -------
    u32x4 af[2];
#pragma unroll
    for (int kk = 0; kk < 2; ++kk) {
      unsigned int a, b2, c2, d2;
      asm("v_cvt_pk_bf16_f32 %0, %1, %2"
          : "=v"(a) : "v"(p[8 * kk + 0]), "v"(p[8 * kk + 1]));
      asm("v_cvt_pk_bf16_f32 %0, %1, %2"
          : "=v"(b2) : "v"(p[8 * kk + 2]), "v"(p[8 * kk + 3]));
      asm("v_cvt_pk_bf16_f32 %0, %1, %2"
          : "=v"(c2) : "v"(p[8 * kk + 4]), "v"(p[8 * kk + 5]));
      asm("v_cvt_pk_bf16_f32 %0, %1, %2"
          : "=v"(d2) : "v"(p[8 * kk + 6]), "v"(p[8 * kk + 7]));
      asm("v_permlane32_swap_b32 %0, %1" : "+v"(a), "+v"(c2));
      asm("v_permlane32_swap_b32 %0, %1" : "+v"(b2), "+v"(d2));
      u32x4 t = {a, b2, c2, d2};
      af[kk] = t;
    }

    // --- O += P . V (V as B-fragment from d-major LDS) --------------------
    __builtin_amdgcn_s_setprio(1);
#pragma unroll
    for (int kk = 0; kk < 2; ++kk)
#pragma unroll
      for (int dt = 0; dt < 4; ++dt) {
        const int d = dt * 32 + l31;
        const int slot = (ksub * 4 + kk * 2 + hl) ^ (d & 7);
        const u32x4 vv = *(const u32x4*)(Vs + (size_t)d * 64 + slot * 8);
        o[dt] = __builtin_amdgcn_mfma_f32_32x32x16_bf16(
            __builtin_bit_cast(bf16x8, af[kk]),
            __builtin_bit_cast(bf16x8, vv), o[dt], 0, 0, 0);
      }
    __builtin_amdgcn_s_setprio(0);

    __syncthreads();  // all LDS reads done before next lwrite overwrites;
                      // also drains the kt+1 prefetch (landed under compute)
  }

  // --- merge key-half partials & write out (reuse idle K/V LDS) -----------
  float* obuf = (float*)(qgrp == 0 ? (void*)Ks : (void*)Vs);  // [32][128]
  if (ksub == 1) {
#pragma unroll
    for (int dt = 0; dt < 4; ++dt)
#pragma unroll
      for (int r = 0; r < 16; ++r) {
        const int qr = (r & 3) + 8 * (r >> 2) + 4 * hl;
        obuf[qr * 128 + dt * 32 + l31] = o[dt][r];
      }
  }
  if (lane < 32) {                          // both halves hold identical m,l
    Ml[wave][lane] = m_i;
    Ml[wave][32 + lane] = l_i;
  }
  __syncthreads();
  if (ksub == 0) {
    float f0[16], f1[16];
#pragma unroll
    for (int r = 0; r < 16; ++r) {
      const int qr = (r & 3) + 8 * (r >> 2) + 4 * hl;
      const float m0 = Ml[wave][qr];
      const float l0 = Ml[wave][32 + qr];
      const float m1 = Ml[wave + 1][qr];
      const float l1 = Ml[wave + 1][32 + qr];
      const float mm = fmaxf(m0, m1);
      const float a0 = exp2f(m0 - mm);      // finite; 0 for dead half
      const float a1 = exp2f(m1 - mm);
      const float li = 1.f / (l0 * a0 + l1 * a1);
      f0[r] = a0 * li;
      f1[r] = a1 * li;
    }
#pragma unroll
    for (int dt = 0; dt < 4; ++dt)
#pragma unroll
      for (int r = 0; r < 16; ++r) {
        const int qr = (r & 3) + 8 * (r >> 2) + 4 * hl;
        const float om =
            o[dt][r] * f0[r] + obuf[qr * 128 + dt * 32 + l31] * f1[r];
        Ob[(size_t)(tokbase + q0 + qgrp * 32 + qr) * HID + hh * DK +
           dt * 32 + l31] = f2bf(om);
      }
  }
}

// ---------------- host ------------------------------------------------------
extern "C" void kernel_launch(void* const* d_in, const int* in_sizes, int n_in,
                              void* d_out, int out_size, void* d_ws, size_t ws_size,
                              hipStream_t stream) {
  const float* x  = (const float*)d_in[0];
  const float* fc = (const float*)d_in[1];
  const float* wq = (const float*)d_in[2];
  const float* wk = (const float*)d_in[3];
  const float* wv = (const float*)d_in[4];
  const float* wo = (const float*)d_in[5];
  float* out = (float*)d_out;

  unsigned short* xb  = (unsigned short*)d_ws;     // [4096][2048]
  unsigned short* wqb = xb  + (size_t)NTOK * HID;  // [2048][2048] each
  unsigned short* wkb = wqb + (size_t)HID * HID;
  unsigned short* wvb = wkb + (size_t)HID * HID;
  unsigned short* wob = wvb + (size_t)HID * HID;
  unsigned short* qb  = wob + (size_t)HID * HID;   // [4096][2048]
  unsigned short* kb  = qb  + (size_t)NTOK * HID;
  unsigned short* vtb = kb  + (size_t)NTOK * HID;  // V^T [32*128][2048]
  unsigned short* ab  = vtb + (size_t)NTOK * HID;  // attn out [4096][2048]
  unsigned int*   fcb = (unsigned int*)(ab + (size_t)NTOK * HID);  // [2048*64]

  convert_all_kernel<<<24576 + 512, 256, 0, stream>>>(
      x, wq, wk, wv, wo, fc, xb, wqb, wkb, wvb, wob, fcb);

  gemm_bt_kernel<false><<<dim3(16, 32), 256, 0, stream>>>(
      xb, wqb, qb, nullptr, fcb, 0);
  gemm_bt_kernel<false><<<dim3(16, 32), 256, 0, stream>>>(
      xb, wkb, kb, nullptr, fcb, 1);
  gemm_bt_kernel<false><<<dim3(16, 32), 256, 0, stream>>>(
      xb, wvb, vtb, nullptr, fcb, 2);

  flash_attn_kernel<<<dim3(1024), 256, 0, stream>>>(qb, kb, vtb, ab);

  gemm_bt_kernel<true><<<dim3(16, 32), 256, 0, stream>>>(
      ab, wob, nullptr, out, fcb, 0);
}